// Round 16
// baseline (282.518 us; speedup 1.0000x reference)
//
#include <hip/hip_runtime.h>
#include <hip/hip_bf16.h>
#include <math.h>

#define BATCH 128
#define LSEQ 24
#define NN 121      // nodes == d_model == out feature
#define SSZ 64      // state size
#define NSTEPS 6
#define BL 3072     // BATCH*LSEQ
#define NT 1024     // mamba block size

typedef _Float16 h16;
typedef _Float16 h16x2 __attribute__((ext_vector_type(2)));
typedef float    fv8  __attribute__((ext_vector_type(8)));

__device__ __forceinline__ h16x2 u2h(uint32_t u) {
    union { uint32_t u; h16x2 h; } c; c.u = u; return c.h;
}
__device__ __forceinline__ uint32_t pack2(float a, float b) {
    union { h16 h; uint16_t u; } x, y; x.h = (h16)a; y.h = (h16)b;
    return (uint32_t)x.u | ((uint32_t)y.u << 16);
}

// ---------------- kernel 1: encoder -> feat[121] (unchanged, verified) ----------------
__global__ __launch_bounds__(256) void enc_kernel(
    const float* __restrict__ x, const float* __restrict__ conv_w,
    const float* __restrict__ conv_b, const float* __restrict__ comp_w1,
    const float* __restrict__ comp_b1, const float* __restrict__ comp_w2,
    const float* __restrict__ comp_b2, float* __restrict__ feat_out)
{
    const int n = blockIdx.x;
    const int tid = threadIdx.x;
    float acc[8] = {0.f,0.f,0.f,0.f,0.f,0.f,0.f,0.f};
    for (int i = tid; i < BL; i += 256) {
        const float xv = x[i * NN + n];
        const float4* w4 = reinterpret_cast<const float4*>(conv_w + i * 8);
        const float4 a = w4[0], b = w4[1];
        acc[0] += xv * a.x; acc[1] += xv * a.y; acc[2] += xv * a.z; acc[3] += xv * a.w;
        acc[4] += xv * b.x; acc[5] += xv * b.y; acc[6] += xv * b.z; acc[7] += xv * b.w;
    }
    __shared__ float red[256][9];
    __shared__ float hred[32];
    #pragma unroll
    for (int j = 0; j < 8; ++j) red[tid][j] = acc[j];
    __syncthreads();
    for (int s = 128; s > 0; s >>= 1) {
        if (tid < s) {
            #pragma unroll
            for (int j = 0; j < 8; ++j) red[tid][j] += red[tid + s][j];
        }
        __syncthreads();
    }
    if (tid < 32) {
        float g[8];
        #pragma unroll
        for (int j = 0; j < 8; ++j) g[j] = red[0][j] + conv_b[j];
        float hsum = comp_b1[tid];
        #pragma unroll
        for (int j = 0; j < 8; ++j)
            hsum += g[j] * (comp_w1[j * 32 + tid] + comp_w1[(j + 8) * 32 + tid]);
        const float hv = hsum > 0.f ? hsum : 0.01f * hsum;
        hred[tid] = hv * comp_w2[tid];
    }
    __syncthreads();
    if (tid == 0) {
        float f = comp_b2[0];
        #pragma unroll
        for (int m = 0; m < 32; ++m) f += hred[m];
        feat_out[n] = f;
    }
}

// ---------------- kernel 2: sequential mamba chain (self-contained weights) --------
__device__ __forceinline__ float softplus_f(float v) {
    return v > 20.f ? v : log1pf(expf(v));
}

// streaming fp32 matvec, 8 row-slices (used once, for adapter)
template<int ROWS, int COLS, int ACT>
__device__ __forceinline__ void matvec8(
    const float* __restrict__ W, const float* __restrict__ bias,
    const float* in, float* out, float* red, int tid)
{
    const int slice = tid >> 7;
    const int j = tid & 127;
    float a0 = 0.f;
    if (j < COLS) {
        const int r0 = (ROWS * slice) >> 3;
        const int r1 = (ROWS * (slice + 1)) >> 3;
        for (int i = r0; i < r1; ++i) a0 += in[i] * W[i * COLS + j];
    }
    red[tid] = a0;
    __syncthreads();
    if (tid < COLS) {
        float s = bias[tid];
        #pragma unroll
        for (int c = 0; c < 8; ++c) s += red[tid + 128 * c];
        if (ACT == 1) s = fmaxf(s, 0.f);
        else if (ACT == 2) s = tanhf(s);
        out[tid] = s;
    }
    __syncthreads();
}

// streamed RAW fp32 matvec, 8 slices x 16 rows; W is R x COLS row-major (original
// layout); rows>=R / cols>=COLS masked (no OOB reads). in = LDS, pads zero.
template<int R, int COLS, int ACT>
__device__ __forceinline__ void stream_mv32(
    const float* __restrict__ W, const float* __restrict__ biasLds,
    const float* in, float* out, float* red, int tid)
{
    const int s = tid >> 7, j = tid & 127;
    const bool jv = (j < COLS);
    float acc = 0.f;
    #pragma unroll
    for (int q = 0; q < 16; ++q) {
        const int r = s * 16 + q;
        const bool v = jv && (r < R);
        acc += v ? in[r] * W[r * COLS + j] : 0.f;
    }
    red[tid] = acc;
    __syncthreads();
    if (tid < COLS) {
        float v = biasLds[tid];
        #pragma unroll
        for (int c = 0; c < 8; ++c) v += red[tid + 128 * c];
        if (ACT == 1) v = fmaxf(v, 0.f);
        else if (ACT == 2) v = tanhf(v);
        out[tid] = v;
    }
    __syncthreads();
}

__global__ __launch_bounds__(NT) void mamba_kernel(
    const float* __restrict__ adapter_w, const float* __restrict__ adapter_b,
    const float* __restrict__ ln_g, const float* __restrict__ ln_b,
    const float* __restrict__ lift_w1, const float* __restrict__ lift_b1,
    const float* __restrict__ lift_w2, const float* __restrict__ lift_b2,
    const float* __restrict__ net_w1,  const float* __restrict__ net_b1,
    const float* __restrict__ net_w2,  const float* __restrict__ net_b2,
    const float* __restrict__ fc1_w,   const float* __restrict__ fc1_b,
    const float* __restrict__ fc2_w,   const float* __restrict__ fc2_b,
    const float* __restrict__ fc3_w,   const float* __restrict__ fc3_b,
    const float* __restrict__ fcout_w, const float* __restrict__ fcout_b,
    const float* __restrict__ Aw, const float* __restrict__ state_init,
    const float* __restrict__ feat_in, float* __restrict__ pred_out)
{
    __shared__ uint32_t WN1[16384];   // 64 KB: net_w1 fp16-pairs [128 pairs][128]
    __shared__ uint32_t WF[16384];    // 64 KB: fused fc fp16-pairs [64 pairs][256]
    __shared__ __align__(16) float catP[256];
    __shared__ __align__(16) float t1[128], t2[128], xtsP[128], outvP[128];
    __shared__ float deltas[128], Bms[64], Cms[64];
    __shared__ float red[NT];
    __shared__ float r128[128], q128[128];
    __shared__ float lb1[128], lb2[128], nb1[128], nb2[128];
    __shared__ float f1b[128], f2b[64], f3b[64], fob[128];
    __shared__ float scal[2];

    const int tid = threadIdx.x;

    // ---- prologue: pack WN1 / WF from fp32 weights directly into LDS ----
    // WN1 word i: pg=i>>7 (row-pair of padded-256), j=i&127;
    //   padded row map: rp<121 -> rp (q part); 128<=rp<249 -> rp-7 (lifted); else 0
    #pragma unroll
    for (int k = 0; k < 16; ++k) {
        const int i = k * NT + tid;
        const int pg = i >> 7, j = i & 127;
        const int rp0 = 2 * pg, rp1 = rp0 + 1;
        const int o0 = rp0 < 121 ? rp0 : (rp0 >= 128 && rp0 < 249 ? rp0 - 7 : -1);
        const int o1 = rp1 < 121 ? rp1 : (rp1 >= 128 && rp1 < 249 ? rp1 - 7 : -1);
        const float v0 = (o0 >= 0) ? net_w1[o0 * 128 + j] : 0.f;
        const float v1 = (o1 >= 0) ? net_w1[o1 * 128 + j] : 0.f;
        WN1[i] = pack2(v0, v1);
    }
    // WF word i: pg=i>>8 (row-pair), j=i&255; cols: [0,121)=fc1, [128,192)=fc2, [192,256)=fc3
    #pragma unroll
    for (int k = 0; k < 16; ++k) {
        const int i = k * NT + tid;
        const int pg = i >> 8, j = i & 255;
        const int rp0 = 2 * pg, rp1 = rp0 + 1;
        float v0 = 0.f, v1 = 0.f;
        if (j < 121) {
            if (rp0 < 121) v0 = fc1_w[rp0 * 121 + j];
            if (rp1 < 121) v1 = fc1_w[rp1 * 121 + j];
        } else if (j >= 128 && j < 192) {
            if (rp0 < 121) v0 = fc2_w[rp0 * 64 + (j - 128)];
            if (rp1 < 121) v1 = fc2_w[rp1 * 64 + (j - 128)];
        } else if (j >= 192) {
            if (rp0 < 121) v0 = fc3_w[rp0 * 64 + (j - 192)];
            if (rp1 < 121) v1 = fc3_w[rp1 * 64 + (j - 192)];
        }
        WF[i] = pack2(v0, v1);
    }

    // per-thread A / h (8 n-values each)
    const int hc = tid >> 7, hd = tid & 127;
    fv8 Areg, hreg;
    #pragma unroll
    for (int k = 0; k < 8; ++k) { Areg[k] = 0.f; hreg[k] = 0.f; }
    if (hd < NN) {
        #pragma unroll
        for (int k = 0; k < 8; ++k) {
            Areg[k] = Aw[hd * SSZ + hc * 8 + k];
            hreg[k] = state_init[hd * SSZ + hc * 8 + k];
        }
    }

    // biases, pads, feat
    if (tid < 128) { lb1[tid] = lift_b1[tid]; nb1[tid] = net_b1[tid]; }
    if (tid < 121) {
        lb2[tid] = lift_b2[tid]; nb2[tid] = net_b2[tid];
        f1b[tid] = fc1_b[tid];   fob[tid] = fcout_b[tid];
        t1[tid] = feat_in[tid];
    }
    if (tid < 64) { f2b[tid] = fc2_b[tid]; f3b[tid] = fc3_b[tid]; }
    if (tid >= 121 && tid < 128) { catP[tid] = 0.f; xtsP[tid] = 0.f; outvP[tid] = 0.f; t2[tid] = 0.f; }
    if (tid >= 249 && tid < 256) catP[tid] = 0.f;
    __syncthreads();

    // adapter: z = feat @ adapter_w + b  (fp32 streamed, once) -> t2
    matvec8<NN, NN, 0>(adapter_w, adapter_b, t1, t2, red, tid);

    // layernorm(t2) -> catP[0..121)
    {
        if (tid < 128) {
            const float v = (tid < NN) ? t2[tid] : 0.f;
            r128[tid] = v; q128[tid] = v * v;
        }
        __syncthreads();
        for (int s = 64; s > 0; s >>= 1) {
            if (tid < s) { r128[tid] += r128[tid + s]; q128[tid] += q128[tid + s]; }
            __syncthreads();
        }
        if (tid == 0) {
            const float mu = r128[0] / (float)NN;
            const float var = q128[0] / (float)NN - mu * mu;
            scal[0] = mu; scal[1] = 1.0f / sqrtf(var + 1e-5f);
        }
        __syncthreads();
        if (tid < NN) catP[tid] = (t2[tid] - scal[0]) * scal[1] * ln_g[tid] + ln_b[tid];
        __syncthreads();
    }

    // ev 0 = warmup (h only), ev 1..6 = steps
    for (int ev = 0; ev < 7; ++ev) {
        stream_mv32<121, 128, 1>(lift_w1, lb1, catP, t1, red, tid);        // relu
        stream_mv32<128, 121, 2>(lift_w2, lb2, t1, catP + 128, red, tid);  // tanh -> lifted

        // net1 from LDS: [128 pairs][128], in = catP[0..256)
        {
            const int s = tid >> 7, j = tid & 127;
            float acc = 0.f;
            #pragma unroll
            for (int p = 0; p < 16; ++p) {
                const h16x2 h = u2h(WN1[(s * 16 + p) * 128 + j]);
                const int r = s * 32 + 2 * p;
                acc += catP[r] * (float)h.x + catP[r + 1] * (float)h.y;
            }
            red[tid] = acc;
            __syncthreads();
            if (tid < 128) {
                float v = nb1[tid];
                #pragma unroll
                for (int c = 0; c < 8; ++c) v += red[tid + 128 * c];
                t2[tid] = fmaxf(v, 0.f);
            }
            __syncthreads();
        }

        stream_mv32<128, 121, 0>(net_w2, nb2, t2, xtsP, red, tid);         // xt

        // fused fc1/fc2/fc3 from LDS: [64 pairs][256], in = xtsP[0..128)
        {
            const int s = tid >> 8, j = tid & 255;
            float acc = 0.f;
            #pragma unroll
            for (int p = 0; p < 16; ++p) {
                const h16x2 h = u2h(WF[(s * 16 + p) * 256 + j]);
                const int r = s * 32 + 2 * p;
                acc += xtsP[r] * (float)h.x + xtsP[r + 1] * (float)h.y;
            }
            red[tid] = acc;
            __syncthreads();
            if (tid < 256) {
                const float val = red[tid] + red[tid + 256] + red[tid + 512] + red[tid + 768];
                if (tid < 121)
                    deltas[tid] = softplus_f(val + f1b[tid]);
                else if (tid >= 128 && tid < 192)
                    Bms[tid - 128] = val + f2b[tid - 128];
                else if (tid >= 192)
                    Cms[tid - 192] = val + f3b[tid - 192];
            }
            __syncthreads();
        }

        // h update + out[d] = sum_n Cm[n]*h_new[d,n]
        {
            float acc = 0.f;
            if (hd < NN) {
                const float dd = deltas[hd];
                const float coef = xtsP[hd] * dd;
                #pragma unroll
                for (int k = 0; k < 8; ++k) {
                    const float s = dd * Areg[k];
                    const float cel = s > 0.f ? s : expm1f(s);   // celu, alpha=1
                    const float dAv = expf(-cel);
                    const float hn = dAv * hreg[k] + coef * Bms[hc * 8 + k];
                    hreg[k] = hn;
                    acc += Cms[hc * 8 + k] * hn;
                }
            }
            red[tid] = acc;
            __syncthreads();
            if (tid < NN) {
                float s = 0.f;
                #pragma unroll
                for (int c = 0; c < 8; ++c) s += red[tid + 128 * c];
                outvP[tid] = s;
            }
            __syncthreads();
        }

        if (ev > 0) {
            stream_mv32<121, 121, 0>(fcout_w, fob, outvP, catP, red, tid); // pred -> q
            if (tid < NN) pred_out[(ev - 1) * NN + tid] = catP[tid];
            __syncthreads();
        }
    }
}

// ---------------- kernel 3: broadcast preds (144 fat blocks, 62 KB each) ------------
__global__ __launch_bounds__(256) void bcast_kernel(
    const float* __restrict__ pred, float* __restrict__ out)
{
    __shared__ float p[128];
    const int blk = blockIdx.x;
    const int s = blk / 24, chunk = blk - s * 24;
    const int t = threadIdx.x;
    if (t < NN) p[t] = pred[s * NN + t];
    __syncthreads();
    float* dst = out + ((long)s * BL + (long)chunk * 128) * NN;
    for (int idx = t; idx < 128 * NN; idx += 256)
        dst[idx] = p[idx % NN];
}

extern "C" void kernel_launch(void* const* d_in, const int* in_sizes, int n_in,
                              void* d_out, int out_size, void* d_ws, size_t ws_size,
                              hipStream_t stream)
{
    const float* x        = (const float*)d_in[0];
    const float* conv_w   = (const float*)d_in[3];
    const float* conv_b   = (const float*)d_in[4];
    const float* comp_w1  = (const float*)d_in[5];
    const float* comp_b1  = (const float*)d_in[6];
    const float* comp_w2  = (const float*)d_in[7];
    const float* comp_b2  = (const float*)d_in[8];
    const float* adapter_w= (const float*)d_in[9];
    const float* adapter_b= (const float*)d_in[10];
    const float* ln_g     = (const float*)d_in[11];
    const float* ln_b     = (const float*)d_in[12];
    const float* lift_w1  = (const float*)d_in[13];
    const float* lift_b1  = (const float*)d_in[14];
    const float* lift_w2  = (const float*)d_in[15];
    const float* lift_b2  = (const float*)d_in[16];
    const float* net_w1   = (const float*)d_in[17];
    const float* net_b1   = (const float*)d_in[18];
    const float* net_w2   = (const float*)d_in[19];
    const float* net_b2   = (const float*)d_in[20];
    const float* fc1_w    = (const float*)d_in[21];
    const float* fc1_b    = (const float*)d_in[22];
    const float* fc2_w    = (const float*)d_in[23];
    const float* fc2_b    = (const float*)d_in[24];
    const float* fc3_w    = (const float*)d_in[25];
    const float* fc3_b    = (const float*)d_in[26];
    const float* Aw       = (const float*)d_in[27];
    const float* state_in = (const float*)d_in[28];
    const float* fcout_w  = (const float*)d_in[29];
    const float* fcout_b  = (const float*)d_in[30];

    float* ws   = (float*)d_ws;
    float* feat = ws;          // 121 floats
    float* pred = ws + 128;    // 6*121 floats

    enc_kernel<<<NN, 256, 0, stream>>>(x, conv_w, conv_b, comp_w1, comp_b1,
                                       comp_w2, comp_b2, feat);
    mamba_kernel<<<1, NT, 0, stream>>>(adapter_w, adapter_b, ln_g, ln_b,
        lift_w1, lift_b1, lift_w2, lift_b2, net_w1, net_b1, net_w2, net_b2,
        fc1_w, fc1_b, fc2_w, fc2_b, fc3_w, fc3_b, fcout_w, fcout_b,
        Aw, state_in, feat, pred);
    bcast_kernel<<<NSTEPS * 24, 256, 0, stream>>>(pred, (float*)d_out);
}